// Round 10
// baseline (252.906 us; speedup 1.0000x reference)
//
#include <hip/hip_runtime.h>

// R9 (resubmit; R9 bench was an infra failure — container acquisition).
// Single change vs the 134.5-us R0 baseline: kC gets
// __launch_bounds__(256, 1). R6's counters showed kC at VGPR_Count=68 —
// the 16xfloat4 emb burst + 16xfloat4 mean gathers (128 VGPRs of results)
// NEVER materialized; the allocator (targeting high occupancy) serialized
// the burst into load-use chains with ~3 outstanding loads/wave ->
// latency-bound 33 us at 2 TB/s. min-waves=1 frees the allocator to hold
// the full burst (~160-190 VGPR, 2-3 waves/SIMD), giving ~32 outstanding
// 1KB requests/wave -> BW-bound ~13 us. kA/kB exact R0 (kA measured at its
// 12.1 us traffic floor in R5). kF stays fused via last-block ticket
// (proven neutral, saves a dispatch).

#define C_SEG 4096
#define E_CH 16
#define NE_EDGES 16384
#define P_PIX (1024 * 1024)
#define NCHUNK 32
#define CHUNK_PIX (P_PIX / NCHUNK)   // 32768
#define SCALE 262144.0f              // 2^18 fixed point
#define INV_SCALE (1.0f / 262144.0f)

// ws layout (byte offsets):
//   0x000000  sums_part[16][32][4096] f32    8 MB
//   0x800000  cnt_part[32][4096]      f32  512 KB
//   0x880000  msum[4096][16]          f32  256 KB   (UNnormalized sums)
//   0x8C0000  inv_n[4096]             f32   16 KB
//   0x8C4000  part[1024]              f32    4 KB
//   0x8C5000  counter                 u32    4 B

__global__ __launch_bounds__(512) void kA(const float* __restrict__ emb,
                                          const int* __restrict__ seg,
                                          float* __restrict__ sums_part,
                                          float* __restrict__ cnt_part) {
    __shared__ int bins[C_SEG];  // 16 KB
    const int chunk = blockIdx.x;
    const int g = blockIdx.y;
    const int t = threadIdx.x;
    const int base = chunk * CHUNK_PIX;

    for (int i = t; i < C_SEG; i += 512) bins[i] = 0;
    __syncthreads();

    if (g == 16) {
        for (int it = 0; it < 16; ++it) {
            const int idx = base + (it * 512 + t) * 4;
            const int4 s4 = *(const int4*)(seg + idx);
            atomicAdd(&bins[s4.x], 1);
            atomicAdd(&bins[s4.y], 1);
            atomicAdd(&bins[s4.z], 1);
            atomicAdd(&bins[s4.w], 1);
        }
        __syncthreads();
        float* cd = cnt_part + (size_t)chunk * C_SEG;
        for (int i = t; i < C_SEG; i += 512) cd[i] = (float)bins[i];
    } else {
        const float* ec = emb + (size_t)g * P_PIX;
        for (int it = 0; it < 16; ++it) {
            const int idx = base + (it * 512 + t) * 4;
            const int4 s4 = *(const int4*)(seg + idx);
            const float4 v = *(const float4*)(ec + idx);
            atomicAdd(&bins[s4.x], __float2int_rn(v.x * SCALE));
            atomicAdd(&bins[s4.y], __float2int_rn(v.y * SCALE));
            atomicAdd(&bins[s4.z], __float2int_rn(v.z * SCALE));
            atomicAdd(&bins[s4.w], __float2int_rn(v.w * SCALE));
        }
        __syncthreads();
        float* dst = sums_part + ((size_t)g * NCHUNK + chunk) * C_SEG;
        for (int i = t; i < C_SEG; i += 512)
            dst[i] = (float)bins[i] * INV_SCALE;
    }
}

__global__ __launch_bounds__(256) void kB(const float* __restrict__ sums_part,
                                          const float* __restrict__ cnt_part,
                                          float* __restrict__ msum,
                                          float* __restrict__ inv_n,
                                          unsigned int* __restrict__ counter) {
    const int vb = blockIdx.x, t = threadIdx.x;
    if (vb == 0 && t == 0) counter[0] = 0u;  // arm kC's last-block ticket
    if (vb < 256) {
        const int c = vb >> 4;
        const int s = (vb & 15) * 256 + t;
        const float* src = sums_part + (size_t)c * NCHUNK * C_SEG + s;
        float acc = 0.0f;
#pragma unroll
        for (int k = 0; k < NCHUNK; ++k) acc += src[(size_t)k * C_SEG];
        msum[s * E_CH + c] = acc;  // UNnormalized
    } else {
        const int s = (vb - 256) * 256 + t;
        float acc = 0.0f;
#pragma unroll
        for (int k = 0; k < NCHUNK; ++k) acc += cnt_part[(size_t)k * C_SEG + s];
        inv_n[s] = 1.0f / fmaxf(acc, 1.0f);
    }
}

// ---------------------------------------------------------------------------
// kC: R0 structure (4 px/thread burst + 16 edges/block, 1024 blocks x 256)
// with __launch_bounds__(256, 1): allocator may use up to 256 VGPRs, so the
// 16x emb float4 + 16x mean float4 burst stays register-resident and all
// ~33 loads/wave are in flight before the first fmaf consumes one.
// ---------------------------------------------------------------------------
__global__ __launch_bounds__(256, 1) void kC(const float* __restrict__ emb,
                                             const int* __restrict__ seg,
                                             const int* __restrict__ edges,
                                             const float* __restrict__ w,
                                             const float* __restrict__ msum,
                                             const float* __restrict__ inv_n,
                                             float* __restrict__ part,
                                             float* __restrict__ out,
                                             unsigned int* __restrict__ counter) {
    const int b = blockIdx.x, t = threadIdx.x;
    const int q = b * 256 + t;  // quad index, 262144 total
    const int4 s4 = *(const int4*)(seg + q * 4);

    // burst-load all 16 emb quads FIRST (longest latency; 64 VGPRs in flight)
    const float4* emb4 = (const float4*)emb;
    float4 e[16];
#pragma unroll
    for (int c = 0; c < 16; ++c) e[c] = emb4[(size_t)c * (P_PIX / 4) + q];

    // then the 4x4 mean-row gathers (L2-hot 256 KB table) + inv_n
    float mA[16], mB[16], mC[16], mD[16];
#pragma unroll
    for (int j = 0; j < 4; ++j) {
        ((float4*)mA)[j] = ((const float4*)(msum + s4.x * E_CH))[j];
        ((float4*)mB)[j] = ((const float4*)(msum + s4.y * E_CH))[j];
        ((float4*)mC)[j] = ((const float4*)(msum + s4.z * E_CH))[j];
        ((float4*)mD)[j] = ((const float4*)(msum + s4.w * E_CH))[j];
    }
    const float inx = inv_n[s4.x], iny = inv_n[s4.y];
    const float inz = inv_n[s4.z], inw = inv_n[s4.w];

    float dx = 0.f, dy = 0.f, dz = 0.f, dw = 0.f;
#pragma unroll
    for (int c = 0; c < 16; ++c) {
        dx = fmaf(e[c].x, mA[c], dx);
        dy = fmaf(e[c].y, mB[c], dy);
        dz = fmaf(e[c].z, mC[c], dz);
        dw = fmaf(e[c].w, mD[c], dw);
    }

    float v = (fmaxf(0.5f - inx * dx, 0.0f) * inx +
               fmaxf(0.5f - iny * dy, 0.0f) * iny +
               fmaxf(0.5f - inz * dz, 0.0f) * inz +
               fmaxf(0.5f - inw * dw, 0.0f) * inw) *
              (1.0f / (float)C_SEG);

    if (t < 16) {  // 16 edges per block
        const int e2 = b * 16 + t;
        const int u = edges[e2];
        const int vv = edges[NE_EDGES + e2];
        const float4* mu = (const float4*)(msum + u * E_CH);
        const float4* mv = (const float4*)(msum + vv * E_CH);
        float dot = 0.0f;
#pragma unroll
        for (int j = 0; j < 4; ++j) {
            const float4 a = mu[j];
            const float4 bb = mv[j];
            dot = fmaf(a.x, bb.x, dot);
            dot = fmaf(a.y, bb.y, dot);
            dot = fmaf(a.z, bb.z, dot);
            dot = fmaf(a.w, bb.w, dot);
        }
        const float d = 1.0f - inv_n[u] * inv_n[vv] * dot;
        v += fmaxf(1.5f - d * w[e2], 0.0f) * (1.0f / (float)NE_EDGES);
    }

    // ---- block reduction (R0/kC exact) ----
    __shared__ float red[4];
    for (int o = 32; o > 0; o >>= 1) v += __shfl_down(v, o, 64);
    if ((t & 63) == 0) red[t >> 6] = v;
    __syncthreads();
    if (t == 0) part[b] = red[0] + red[1] + red[2] + red[3];

    // ---- fused kF: last of 1024 blocks replays old kF byte-for-byte ----
    __threadfence();
    __shared__ unsigned int tick;
    if (t == 0) tick = atomicAdd(counter, 1u);
    __syncthreads();
    if (tick == 1023u) {
        __threadfence();
        float v2 = 0.0f;
        for (int i = t; i < 1024; i += 256) v2 += part[i];
        for (int o = 32; o > 0; o >>= 1) v2 += __shfl_down(v2, o, 64);
        __shared__ float red2[4];
        if ((t & 63) == 0) red2[t >> 6] = v2;
        __syncthreads();
        if (t == 0) {
            out[0] = red2[0] + red2[1] + red2[2] + red2[3];
            counter[0] = 0u;
        }
    }
}

extern "C" void kernel_launch(void* const* d_in, const int* in_sizes, int n_in,
                              void* d_out, int out_size, void* d_ws,
                              size_t ws_size, hipStream_t stream) {
    const float* emb = (const float*)d_in[0];      // (1,16,1024,1024) fp32
    const float* weights = (const float*)d_in[1];  // (16384,) fp32
    const int* seg = (const int*)d_in[2];          // (1,1,1024,1024) int32
    const int* edges = (const int*)d_in[3];        // (2,16384) int32
    float* out = (float*)d_out;

    char* ws = (char*)d_ws;
    float* sums_part = (float*)(ws);
    float* cnt_part = (float*)(ws + 0x800000);
    float* msum = (float*)(ws + 0x880000);
    float* invn = (float*)(ws + 0x8C0000);
    float* part = (float*)(ws + 0x8C4000);
    unsigned int* counter = (unsigned int*)(ws + 0x8C5000);

    dim3 gA(NCHUNK, 17);
    kA<<<gA, 512, 0, stream>>>(emb, seg, sums_part, cnt_part);
    kB<<<272, 256, 0, stream>>>(sums_part, cnt_part, msum, invn, counter);
    kC<<<1024, 256, 0, stream>>>(emb, seg, edges, weights, msum, invn, part, out, counter);
}

// Round 11
// 132.317 us; speedup vs baseline: 1.9114x; 1.9114x over previous
//
#include <hip/hip_runtime.h>

// R11: kC rebuilt channel-major. Evidence: every thread-strided kC variant
// (R0/R6/R7/R8) sits at ~33 us / ~2 TB/s; kA streams the SAME bytes at
// 6.3 TB/s with waves contiguous inside ONE channel plane. The 4-MB
// (2^22 B) per-thread stride aliases all 16 streams onto the same L2/L3
// channel bits + DRAM pages -> channel-serialized. New kC: loop channels,
// one contiguous float4 per thread per step from plane c (kA's pattern),
// mean column c staged in 16 KB LDS (gathers become ds_read), next-step
// emb+mean loads issued before compute (T14 split). Per-pixel fmaf order
// unchanged (c ascending, same accumulator) -> dots bit-identical.
// R10 lesson: NO min-waves arg in launch_bounds (256,1 collapsed codegen
// to 36 VGPR / 150 us).

#define C_SEG 4096
#define E_CH 16
#define NE_EDGES 16384
#define P_PIX (1024 * 1024)
#define NCHUNK 32
#define CHUNK_PIX (P_PIX / NCHUNK)   // 32768
#define SCALE 262144.0f              // 2^18 fixed point
#define INV_SCALE (1.0f / 262144.0f)

// ws layout (byte offsets):
//   0x000000  sums_part[16][32][4096] f32    8 MB
//   0x800000  cnt_part[32][4096]      f32  512 KB
//   0x880000  msum[4096][16]          f32  256 KB  (row-major, for edges)
//   0x8C0000  meanT[16][4096]         f32  256 KB  (transposed, for kC staging)
//   0x900000  inv_n[4096]             f32   16 KB
//   0x904000  part[512]               f32    2 KB
//   0x905000  counter                 u32    4 B

__global__ __launch_bounds__(512) void kA(const float* __restrict__ emb,
                                          const int* __restrict__ seg,
                                          float* __restrict__ sums_part,
                                          float* __restrict__ cnt_part) {
    __shared__ int bins[C_SEG];  // 16 KB
    const int chunk = blockIdx.x;
    const int g = blockIdx.y;
    const int t = threadIdx.x;
    const int base = chunk * CHUNK_PIX;

    for (int i = t; i < C_SEG; i += 512) bins[i] = 0;
    __syncthreads();

    if (g == 16) {
        for (int it = 0; it < 16; ++it) {
            const int idx = base + (it * 512 + t) * 4;
            const int4 s4 = *(const int4*)(seg + idx);
            atomicAdd(&bins[s4.x], 1);
            atomicAdd(&bins[s4.y], 1);
            atomicAdd(&bins[s4.z], 1);
            atomicAdd(&bins[s4.w], 1);
        }
        __syncthreads();
        float* cd = cnt_part + (size_t)chunk * C_SEG;
        for (int i = t; i < C_SEG; i += 512) cd[i] = (float)bins[i];
    } else {
        const float* ec = emb + (size_t)g * P_PIX;
        for (int it = 0; it < 16; ++it) {
            const int idx = base + (it * 512 + t) * 4;
            const int4 s4 = *(const int4*)(seg + idx);
            const float4 v = *(const float4*)(ec + idx);
            atomicAdd(&bins[s4.x], __float2int_rn(v.x * SCALE));
            atomicAdd(&bins[s4.y], __float2int_rn(v.y * SCALE));
            atomicAdd(&bins[s4.z], __float2int_rn(v.z * SCALE));
            atomicAdd(&bins[s4.w], __float2int_rn(v.w * SCALE));
        }
        __syncthreads();
        float* dst = sums_part + ((size_t)g * NCHUNK + chunk) * C_SEG;
        for (int i = t; i < C_SEG; i += 512)
            dst[i] = (float)bins[i] * INV_SCALE;
    }
}

__global__ __launch_bounds__(256) void kB(const float* __restrict__ sums_part,
                                          const float* __restrict__ cnt_part,
                                          float* __restrict__ msum,
                                          float* __restrict__ meanT,
                                          float* __restrict__ inv_n,
                                          unsigned int* __restrict__ counter) {
    const int vb = blockIdx.x, t = threadIdx.x;
    if (vb == 0 && t == 0) counter[0] = 0u;  // arm kC's last-block ticket
    if (vb < 256) {
        const int c = vb >> 4;
        const int s = (vb & 15) * 256 + t;
        const float* src = sums_part + (size_t)c * NCHUNK * C_SEG + s;
        float acc = 0.0f;
#pragma unroll
        for (int k = 0; k < NCHUNK; ++k) acc += src[(size_t)k * C_SEG];
        msum[s * E_CH + c] = acc;             // row-major (edges)
        meanT[c * C_SEG + s] = acc;           // transposed (kC staging, coalesced)
    } else {
        const int s = (vb - 256) * 256 + t;
        float acc = 0.0f;
#pragma unroll
        for (int k = 0; k < NCHUNK; ++k) acc += cnt_part[(size_t)k * C_SEG + s];
        inv_n[s] = 1.0f / fmaxf(acc, 1.0f);
    }
}

// ---------------------------------------------------------------------------
// kC: 512 blocks x 512 threads, 4 px/thread (block = 2048 contiguous px).
// Channel-major: per step c, thread reads ONE contiguous float4 from plane
// c (wave = 1 KB contiguous in a single plane = kA's 6.3 TB/s pattern) and
// 4 mean values from the LDS-staged column c. Next step's emb float4 and
// mean column are issued BEFORE this step's compute (async-stage split).
// ---------------------------------------------------------------------------
__global__ __launch_bounds__(512) void kC(const float* __restrict__ emb,
                                          const int* __restrict__ seg,
                                          const int* __restrict__ edges,
                                          const float* __restrict__ w,
                                          const float* __restrict__ msum,
                                          const float* __restrict__ meanT,
                                          const float* __restrict__ inv_n,
                                          float* __restrict__ part,
                                          float* __restrict__ out,
                                          unsigned int* __restrict__ counter) {
    __shared__ float mcol[C_SEG];  // 16 KB: mean column c (then inv_n)
    __shared__ float red[8];
    __shared__ unsigned int tick;
    const int b = blockIdx.x, t = threadIdx.x;
    const int pbase = b * 2048;          // block's pixel tile
    const int p0 = pbase + t * 4;        // this thread's 4 contiguous pixels
    const int4 sq = *(const int4*)(seg + p0);

    // prologue: stage column 0, prefetch emb plane-0 quad
    float4 sA = *(const float4*)(meanT + t * 4);
    float4 sB = *(const float4*)(meanT + 2048 + t * 4);
    *(float4*)(mcol + t * 4) = sA;
    *(float4*)(mcol + 2048 + t * 4) = sB;
    float4 eA = *(const float4*)(emb + p0);

    float d0 = 0.f, d1 = 0.f, d2 = 0.f, d3 = 0.f;

#pragma unroll
    for (int c = 0; c < 16; ++c) {
        __syncthreads();  // mcol[c] visible
        float4 eN, nA, nB;
        if (c < 15) {     // issue next-step loads early (hide under compute)
            eN = *(const float4*)(emb + (size_t)(c + 1) * P_PIX + p0);
            nA = *(const float4*)(meanT + (size_t)(c + 1) * C_SEG + t * 4);
            nB = *(const float4*)(meanT + (size_t)(c + 1) * C_SEG + 2048 + t * 4);
        }
        const float m0 = mcol[sq.x];
        const float m1 = mcol[sq.y];
        const float m2 = mcol[sq.z];
        const float m3 = mcol[sq.w];
        d0 = fmaf(eA.x, m0, d0);
        d1 = fmaf(eA.y, m1, d1);
        d2 = fmaf(eA.z, m2, d2);
        d3 = fmaf(eA.w, m3, d3);
        __syncthreads();  // mcol reads done
        if (c < 15) {
            *(float4*)(mcol + t * 4) = nA;
            *(float4*)(mcol + 2048 + t * 4) = nB;
            eA = eN;
        }
    }

    // stage inv_n into the same buffer, gather per-pixel
    __syncthreads();
    *(float4*)(mcol + t * 4) = *(const float4*)(inv_n + t * 4);
    *(float4*)(mcol + 2048 + t * 4) = *(const float4*)(inv_n + 2048 + t * 4);
    __syncthreads();
    const float in0 = mcol[sq.x], in1 = mcol[sq.y];
    const float in2 = mcol[sq.z], in3 = mcol[sq.w];

    float v = (fmaxf(0.5f - in0 * d0, 0.0f) * in0 +
               fmaxf(0.5f - in1 * d1, 0.0f) * in1 +
               fmaxf(0.5f - in2 * d2, 0.0f) * in2 +
               fmaxf(0.5f - in3 * d3, 0.0f) * in3) *
              (1.0f / (float)C_SEG);

    if (t < 32) {  // 32 edges per block (512 x 32 = 16384)
        const int e2 = b * 32 + t;
        const int u = edges[e2];
        const int vv = edges[NE_EDGES + e2];
        const float4* mu = (const float4*)(msum + u * E_CH);
        const float4* mv = (const float4*)(msum + vv * E_CH);
        float dot = 0.0f;
#pragma unroll
        for (int j = 0; j < 4; ++j) {
            const float4 a = mu[j];
            const float4 bb = mv[j];
            dot = fmaf(a.x, bb.x, dot);
            dot = fmaf(a.y, bb.y, dot);
            dot = fmaf(a.z, bb.z, dot);
            dot = fmaf(a.w, bb.w, dot);
        }
        const float d = 1.0f - inv_n[u] * inv_n[vv] * dot;
        v += fmaxf(1.5f - d * w[e2], 0.0f) * (1.0f / (float)NE_EDGES);
    }

    // ---- block reduction (8 waves) ----
    for (int o = 32; o > 0; o >>= 1) v += __shfl_down(v, o, 64);
    if ((t & 63) == 0) red[t >> 6] = v;
    __syncthreads();
    if (t == 0) {
        float s = 0.0f;
#pragma unroll
        for (int i = 0; i < 8; ++i) s += red[i];
        part[b] = s;
        __threadfence();
        tick = atomicAdd(counter, 1u);
    }
    __syncthreads();

    // ---- fused kF: last of 512 blocks sums part[] in index order ----
    if (tick == 511u) {
        __threadfence();
        float v2 = part[t];  // 512 threads, one partial each
        for (int o = 32; o > 0; o >>= 1) v2 += __shfl_down(v2, o, 64);
        if ((t & 63) == 0) red[t >> 6] = v2;
        __syncthreads();
        if (t == 0) {
            float s = 0.0f;
#pragma unroll
            for (int i = 0; i < 8; ++i) s += red[i];
            out[0] = s;
            counter[0] = 0u;
        }
    }
}

extern "C" void kernel_launch(void* const* d_in, const int* in_sizes, int n_in,
                              void* d_out, int out_size, void* d_ws,
                              size_t ws_size, hipStream_t stream) {
    const float* emb = (const float*)d_in[0];      // (1,16,1024,1024) fp32
    const float* weights = (const float*)d_in[1];  // (16384,) fp32
    const int* seg = (const int*)d_in[2];          // (1,1,1024,1024) int32
    const int* edges = (const int*)d_in[3];        // (2,16384) int32
    float* out = (float*)d_out;

    char* ws = (char*)d_ws;
    float* sums_part = (float*)(ws);
    float* cnt_part = (float*)(ws + 0x800000);
    float* msum = (float*)(ws + 0x880000);
    float* meanT = (float*)(ws + 0x8C0000);
    float* invn = (float*)(ws + 0x900000);
    float* part = (float*)(ws + 0x904000);
    unsigned int* counter = (unsigned int*)(ws + 0x905000);

    dim3 gA(NCHUNK, 17);
    kA<<<gA, 512, 0, stream>>>(emb, seg, sums_part, cnt_part);
    kB<<<272, 256, 0, stream>>>(sums_part, cnt_part, msum, meanT, invn, counter);
    kC<<<512, 512, 0, stream>>>(emb, seg, edges, weights, msum, meanT, invn, part, out, counter);
}